// Round 2
// baseline (3208.255 us; speedup 1.0000x reference)
//
#include <hip/hip_runtime.h>
#include <stdint.h>

// FastRNN: B=64, T=512, I=256, H=512, fp32.
//   K1: wx = x @ W + bias  (bf16 MFMA GEMM) — unchanged.
//   K2: h_t = sb*h + sa*tanh(wx_t + h @ U), 16 blocks = 4 batch-groups x
//       4 j-slices, U register-resident bf16 B-frags, self-validating
//       tagged-bf16 h exchange (tag in each half's mantissa LSB).
// R8 (retreat from R7's barrier-free attempt, which guard-expired):
//   Keep R6's proven skeleton (barriers C and F, block-unit publish, tag
//   protocol identical). Two provably-safe changes only:
//   (1) Poll DIRECTLY into per-lane A-frag registers (32 tagged u64s/lane
//       = the 16 v8s MFMA A operands). Deletes the Als LDS round-trip:
//       no staging writes, no 16x ds_read_b128/lane (bulk of the 5.9M
//       bank-conflict cycles), no LDS latency between poll and MFMA.
//       Zero cross-lane dataflow added; barrier C semantics unchanged.
//   (2) Next-step frag loads issued right after publish (speculative,
//       re-validated by the tag poll — same check-then-reload semantics),
//       hiding most of the LLC RT under the loop tail.

#define B_ 64
#define T_ 512
#define I_ 256
#define H_ 512
#define M_ (B_ * T_)  // 32768

#define WXB_BYTES  ((size_t)M_ * H_ * 4)       // 64 MiB fp32
#define HHALF_BYTES ((size_t)B_ * H_ * 2)      // 64 KiB bf16 per parity

typedef short v8s __attribute__((ext_vector_type(8)));
typedef float v4f __attribute__((ext_vector_type(4)));
typedef unsigned long long u64t;

__device__ __forceinline__ uint16_t f2bf(float x) {
    union { float f; uint32_t u; } v; v.f = x;
    return (uint16_t)((v.u + 0x7FFFu + ((v.u >> 16) & 1u)) >> 16);
}

// --------------- K1: wxb[m][j] = x[m][:] @ W[:][j] + bias[j] ----------------
__global__ __launch_bounds__(256) void wx_gemm(
        const float* __restrict__ x, const float* __restrict__ W,
        const float* __restrict__ bias, float* __restrict__ wxb) {
    __shared__ uint16_t Asl[64][40];
    __shared__ uint16_t Bsl[4 * 64 * 8];

    const int tid = threadIdx.x;
    const int lane = tid & 63;
    const int w = tid >> 6;
    const int q = lane >> 4, c = lane & 15;
    const int mbase = (int)(blockIdx.x >> 3) * 64;
    const int nbase = (int)(blockIdx.x & 7) * 64;

    v4f acc[4];
    #pragma unroll
    for (int i = 0; i < 4; ++i) acc[i] = (v4f){0.f, 0.f, 0.f, 0.f};

    for (int ks = 0; ks < I_; ks += 32) {
        {
            int row = tid >> 2, c4 = tid & 3;
            const float* gp = x + (size_t)(mbase + row) * I_ + ks + c4 * 8;
            float4 f0 = *(const float4*)gp;
            float4 f1 = *(const float4*)(gp + 4);
            uint16_t* dp = &Asl[row][c4 * 8];
            dp[0] = f2bf(f0.x); dp[1] = f2bf(f0.y); dp[2] = f2bf(f0.z); dp[3] = f2bf(f0.w);
            dp[4] = f2bf(f1.x); dp[5] = f2bf(f1.y); dp[6] = f2bf(f1.z); dp[7] = f2bf(f1.w);
        }
        {
            int nt = tid >> 6;
            const float* gp = W + (size_t)(ks + q * 8) * H_ + nbase + nt * 16 + c;
            union { v8s v; uint16_t u[8]; } pk;
            #pragma unroll
            for (int jj = 0; jj < 8; ++jj) pk.u[jj] = f2bf(gp[(size_t)jj * H_]);
            *(v8s*)&Bsl[(nt * 64 + lane) * 8] = pk.v;
        }
        __syncthreads();
        const v8s* Bf = (const v8s*)Bsl;
        v8s a = *(const v8s*)&Asl[w * 16 + c][q * 8];
        #pragma unroll
        for (int nt = 0; nt < 4; ++nt) {
            v8s b = Bf[nt * 64 + lane];
            acc[nt] = __builtin_amdgcn_mfma_f32_16x16x32_bf16(a, b, acc[nt], 0, 0, 0);
        }
        __syncthreads();
    }
    #pragma unroll
    for (int nt = 0; nt < 4; ++nt) {
        int j = nbase + nt * 16 + c;
        float bj = bias[j];
        #pragma unroll
        for (int r = 0; r < 4; ++r) {
            int m = mbase + w * 16 + q * 4 + r;
            wxb[(size_t)m * H_ + j] = acc[nt][r] + bj;
        }
    }
}

// --------------- K2: recurrent scan ----------------------------------------
__global__ __launch_bounds__(256, 1) void rnn_scan(
        const float* __restrict__ U, const float* __restrict__ wxb,
        const float* __restrict__ alpha, const float* __restrict__ beta,
        float* __restrict__ out, uint16_t* __restrict__ Hbuf) {
    __shared__ uint16_t Hstg[16][128];    // this block's tagged h_new (bf16)

    const int bid = blockIdx.x;
    const int g = bid >> 2, s = bid & 3;
    const int tid = threadIdx.x;
    const int lane = tid & 63;
    const int w = tid >> 6;
    const int q = lane >> 4, c = lane & 15;

    float sa, sb;
    { float a = alpha[0], b = beta[0];
      sa = 1.f / (1.f + __expf(-a)); sb = 1.f / (1.f + __expf(-b)); }

    // Loop-invariant U B-frags: wave w owns ntiles 2w, 2w+1 of our 128-col slice.
    v8s Uf[2][16];
    #pragma unroll
    for (int nt = 0; nt < 2; ++nt) {
        int jg = s * 128 + (2 * w + nt) * 16 + c;
        #pragma unroll
        for (int kt = 0; kt < 16; ++kt) {
            const float* gp = U + (size_t)(kt * 32 + q * 8) * H_ + jg;
            union { v8s v; uint16_t u[8]; } pk;
            #pragma unroll
            for (int jj = 0; jj < 8; ++jj) pk.u[jj] = f2bf(gp[(size_t)jj * H_]);
            Uf[nt][kt] = pk.v;
        }
    }
    float hold[2][4];
    #pragma unroll
    for (int nt = 0; nt < 2; ++nt)
        #pragma unroll
        for (int r = 0; r < 4; ++r) hold[nt][r] = 0.f;

    // wx prefetch: one step ahead (loads issued ~1 step before consumption).
    float wxv[2][4], wxn[2][4];
    #pragma unroll
    for (int nt = 0; nt < 2; ++nt) {
        int jg = s * 128 + (2 * w + nt) * 16 + c;
        #pragma unroll
        for (int r = 0; r < 4; ++r) {
            int bg = g * 16 + q * 4 + r;
            wxn[nt][r] = __builtin_nontemporal_load(
                &wxb[((size_t)bg * T_ + 0) * H_ + jg]);
        }
    }

    // Per-lane A-frag base: row g*16+c, col base q*8. Frag kt = u64s
    // abase + kt*8 + {0,1}  (cols kt*32+q*8 .. +7) — the exact MFMA A layout.
    const size_t abase = ((size_t)(g * 16 + c) * H_ + q * 8) >> 2;  // u64 units

    u64t av[16][2];
    #pragma unroll
    for (int kt = 0; kt < 16; ++kt) { av[kt][0] = 0; av[kt][1] = 0; }  // h_0 = 0

    for (int t = 0; t < T_; ++t) {
        const int p = t & 1;
        // rotate wx prefetch buffer
        #pragma unroll
        for (int nt = 0; nt < 2; ++nt)
            #pragma unroll
            for (int r = 0; r < 4; ++r) wxv[nt][r] = wxn[nt][r];

        // ---- poll: validate per-lane A-frags (loads issued at end of t-1);
        //      spin-reload until every 16-bit half carries tag tau ----
        if (t > 0) {
            const u64t* gp = (const u64t*)Hbuf + (size_t)p * (B_ * H_ / 4) + abase;
            const uint32_t tau = (uint32_t)((t >> 1) & 1);
            for (int guard = 0; guard < (1 << 20); ++guard) {
                u64t x;
                if (tau) {
                    u64t a64 = av[0][0] & av[0][1];
                    #pragma unroll
                    for (int kt = 1; kt < 16; ++kt) { a64 &= av[kt][0]; a64 &= av[kt][1]; }
                    x = ~a64;
                } else {
                    u64t o64 = av[0][0] | av[0][1];
                    #pragma unroll
                    for (int kt = 1; kt < 16; ++kt) { o64 |= av[kt][0]; o64 |= av[kt][1]; }
                    x = o64;
                }
                uint32_t fold = (uint32_t)(x | (x >> 32));
                if (!((fold | (fold >> 16)) & 1u)) break;
                #pragma unroll
                for (int kt = 0; kt < 16; ++kt) {   // batch reload: 1 RT per spin
                    av[kt][0] = __hip_atomic_load(&gp[kt * 8 + 0], __ATOMIC_RELAXED,
                                                  __HIP_MEMORY_SCOPE_AGENT);
                    av[kt][1] = __hip_atomic_load(&gp[kt * 8 + 1], __ATOMIC_RELAXED,
                                                  __HIP_MEMORY_SCOPE_AGENT);
                }
            }
        }
        __syncthreads();  // C: all waves validated (R6 drift-bound semantics)
        // ---- prefetch wx for t+1 (max distance from the next poll wait) ----
        if (t + 1 < T_) {
            #pragma unroll
            for (int nt = 0; nt < 2; ++nt) {
                int jg = s * 128 + (2 * w + nt) * 16 + c;
                #pragma unroll
                for (int r = 0; r < 4; ++r) {
                    int bg = g * 16 + q * 4 + r;
                    wxn[nt][r] = __builtin_nontemporal_load(
                        &wxb[((size_t)bg * T_ + (t + 1)) * H_ + jg]);
                }
            }
        }
        // ---- P = H @ U_slice : 4 accumulator chains (depth 8 each) ----
        v4f acc00 = (v4f){0.f, 0.f, 0.f, 0.f};
        v4f acc01 = (v4f){0.f, 0.f, 0.f, 0.f};
        v4f acc10 = (v4f){0.f, 0.f, 0.f, 0.f};
        v4f acc11 = (v4f){0.f, 0.f, 0.f, 0.f};
        #pragma unroll
        for (int kt = 0; kt < 16; kt += 2) {
            union { u64t u[2]; v8s v; } f0, f1;
            f0.u[0] = av[kt][0];     f0.u[1] = av[kt][1];
            f1.u[0] = av[kt + 1][0]; f1.u[1] = av[kt + 1][1];
            acc00 = __builtin_amdgcn_mfma_f32_16x16x32_bf16(f0.v, Uf[0][kt],     acc00, 0, 0, 0);
            acc10 = __builtin_amdgcn_mfma_f32_16x16x32_bf16(f0.v, Uf[1][kt],     acc10, 0, 0, 0);
            acc01 = __builtin_amdgcn_mfma_f32_16x16x32_bf16(f1.v, Uf[0][kt + 1], acc01, 0, 0, 0);
            acc11 = __builtin_amdgcn_mfma_f32_16x16x32_bf16(f1.v, Uf[1][kt + 1], acc11, 0, 0, 0);
        }
        v4f accA = acc00 + acc01;
        v4f accB = acc10 + acc11;

        // ---- epilogue: fp32 state in regs; tagged bf16 -> Hstg (R6 exact) ----
        const uint16_t tauw = (uint16_t)(((t + 1) >> 1) & 1);
        #pragma unroll
        for (int nt = 0; nt < 2; ++nt) {
            int jl = (2 * w + nt) * 16 + c;
            #pragma unroll
            for (int r = 0; r < 4; ++r) {
                float pre = (nt ? accB[r] : accA[r]) + wxv[nt][r];
                float ex = __expf(pre + pre);                           // e^{2x}
                float ct = 1.f - 2.f * __builtin_amdgcn_rcpf(ex + 1.f); // tanh
                float hn = sb * hold[nt][r] + sa * ct;
                hold[nt][r] = hn;
                Hstg[q * 4 + r][jl] = (uint16_t)((f2bf(hn) & 0xFFFEu) | tauw);
            }
        }
        __syncthreads();  // F: Hstg complete
        // ---- publish packed 16 B/thread (relaxed agent atomics, R6 exact) ----
        {
            int i0 = tid * 2;
            #pragma unroll
            for (int k2 = 0; k2 < 2; ++k2) {
                int i = i0 + k2;
                int b = i >> 5, jo = (i & 31) * 4;
                u64t v = *(const u64t*)&Hstg[b][jo];
                u64t* pp = (u64t*)(Hbuf +
                    ((size_t)(1 - p) * B_ + g * 16 + b) * H_ + s * 128 + jo);
                __hip_atomic_store(pp, v, __ATOMIC_RELAXED,
                                   __HIP_MEMORY_SCOPE_AGENT);
            }
        }
        // ---- early-issue next-step frag loads: first LLC RT overlaps the
        //      loop tail; stale data is caught by the next tag poll ----
        if (t + 1 < T_) {
            const u64t* gn = (const u64t*)Hbuf + (size_t)(1 - p) * (B_ * H_ / 4) + abase;
            #pragma unroll
            for (int kt = 0; kt < 16; ++kt) {
                av[kt][0] = __hip_atomic_load(&gn[kt * 8 + 0], __ATOMIC_RELAXED,
                                              __HIP_MEMORY_SCOPE_AGENT);
                av[kt][1] = __hip_atomic_load(&gn[kt * 8 + 1], __ATOMIC_RELAXED,
                                              __HIP_MEMORY_SCOPE_AGENT);
            }
        }
        // ---- out stores — PLAIN (retire in local L2, off the critical path) ----
        #pragma unroll
        for (int nt = 0; nt < 2; ++nt) {
            int jg = s * 128 + (2 * w + nt) * 16 + c;
            #pragma unroll
            for (int r = 0; r < 4; ++r) {
                int bg = g * 16 + q * 4 + r;
                out[((size_t)bg * T_ + t) * H_ + jg] = hold[nt][r];
            }
        }
    }
}

extern "C" void kernel_launch(void* const* d_in, const int* in_sizes, int n_in,
                              void* d_out, int out_size, void* d_ws, size_t ws_size,
                              hipStream_t stream) {
    const float* x     = (const float*)d_in[0];
    const float* W     = (const float*)d_in[1];
    const float* U     = (const float*)d_in[2];
    const float* bias  = (const float*)d_in[3];
    const float* alpha = (const float*)d_in[4];
    const float* beta  = (const float*)d_in[5];
    float* out = (float*)d_out;

    char* ws = (char*)d_ws;
    float* wxb = (float*)ws;                                  // 64 MiB
    uint16_t* Hbuf = (uint16_t*)(ws + WXB_BYTES);             // 128 KiB tagged bf16

    // Warm-up tag safety: parity 0 halves get LSB=0 (invalid at t'=2 which
    // expects tau=1), parity 1 halves get LSB=1 (invalid at t'=1, tau=0).
    hipMemsetAsync(Hbuf, 0x00, HHALF_BYTES, stream);
    hipMemsetAsync((char*)Hbuf + HHALF_BYTES, 0xFF, HHALF_BYTES, stream);

    wx_gemm<<<dim3((M_ / 64) * (H_ / 64)), dim3(256), 0, stream>>>(x, W, bias, wxb);
    rnn_scan<<<dim3(16), dim3(256), 0, stream>>>(U, wxb, alpha, beta, out, Hbuf);
}

// Round 3
// 1301.478 us; speedup vs baseline: 2.4651x; 2.4651x over previous
//
#include <hip/hip_runtime.h>
#include <stdint.h>

// FastRNN: B=64, T=512, I=256, H=512, fp32.
//   K1: wx = x @ W + bias  (bf16 MFMA GEMM) — unchanged.
//   K2: h_t = sb*h + sa*tanh(wx_t + h @ U), 16 blocks = 4 batch-groups x
//       4 j-slices, U register-resident bf16 B-frags, self-validating
//       tagged-bf16 h exchange (tag in each half's mantissa LSB).
// R9: R6 skeleton (barriers C+F, LDS A-staging, tag protocol) with the
//   h-exchange made LLC-transaction-efficient:
//   (1) poll remapped to lane-contiguous 16B chunks (k = tid + 256*u4):
//       each wave instr = 1KB contiguous -> 4-lane granule merge (was 64B
//       lane-stride 8B atomic loads: 64 granules/instr, ~8x the txns).
//       Inline-asm global_load_dwordx4 sc0 sc1 (same coherence path).
//   (2) publish = one global_store_dwordx4 sc0 sc1 per thread (lane-
//       contiguous 256B runs; was 2x strided 8B atomic stores).
//   (3) poll loads for t+1 issued at tail of t (after publish) —
//       speculative, re-validated by tags (R8's proven-safe half).

#define B_ 64
#define T_ 512
#define I_ 256
#define H_ 512
#define M_ (B_ * T_)  // 32768

#define WXB_BYTES  ((size_t)M_ * H_ * 4)       // 64 MiB fp32
#define HHALF_BYTES ((size_t)B_ * H_ * 2)      // 64 KiB bf16 per parity

typedef short v8s __attribute__((ext_vector_type(8)));
typedef float v4f __attribute__((ext_vector_type(4)));
typedef unsigned int u32x4 __attribute__((ext_vector_type(4)));
typedef unsigned long long u64t;

__device__ __forceinline__ uint16_t f2bf(float x) {
    union { float f; uint32_t u; } v; v.f = x;
    return (uint16_t)((v.u + 0x7FFFu + ((v.u >> 16) & 1u)) >> 16);
}

// --------------- K1: wxb[m][j] = x[m][:] @ W[:][j] + bias[j] ----------------
__global__ __launch_bounds__(256) void wx_gemm(
        const float* __restrict__ x, const float* __restrict__ W,
        const float* __restrict__ bias, float* __restrict__ wxb) {
    __shared__ uint16_t Asl[64][40];
    __shared__ uint16_t Bsl[4 * 64 * 8];

    const int tid = threadIdx.x;
    const int lane = tid & 63;
    const int w = tid >> 6;
    const int q = lane >> 4, c = lane & 15;
    const int mbase = (int)(blockIdx.x >> 3) * 64;
    const int nbase = (int)(blockIdx.x & 7) * 64;

    v4f acc[4];
    #pragma unroll
    for (int i = 0; i < 4; ++i) acc[i] = (v4f){0.f, 0.f, 0.f, 0.f};

    for (int ks = 0; ks < I_; ks += 32) {
        {
            int row = tid >> 2, c4 = tid & 3;
            const float* gp = x + (size_t)(mbase + row) * I_ + ks + c4 * 8;
            float4 f0 = *(const float4*)gp;
            float4 f1 = *(const float4*)(gp + 4);
            uint16_t* dp = &Asl[row][c4 * 8];
            dp[0] = f2bf(f0.x); dp[1] = f2bf(f0.y); dp[2] = f2bf(f0.z); dp[3] = f2bf(f0.w);
            dp[4] = f2bf(f1.x); dp[5] = f2bf(f1.y); dp[6] = f2bf(f1.z); dp[7] = f2bf(f1.w);
        }
        {
            int nt = tid >> 6;
            const float* gp = W + (size_t)(ks + q * 8) * H_ + nbase + nt * 16 + c;
            union { v8s v; uint16_t u[8]; } pk;
            #pragma unroll
            for (int jj = 0; jj < 8; ++jj) pk.u[jj] = f2bf(gp[(size_t)jj * H_]);
            *(v8s*)&Bsl[(nt * 64 + lane) * 8] = pk.v;
        }
        __syncthreads();
        const v8s* Bf = (const v8s*)Bsl;
        v8s a = *(const v8s*)&Asl[w * 16 + c][q * 8];
        #pragma unroll
        for (int nt = 0; nt < 4; ++nt) {
            v8s b = Bf[nt * 64 + lane];
            acc[nt] = __builtin_amdgcn_mfma_f32_16x16x32_bf16(a, b, acc[nt], 0, 0, 0);
        }
        __syncthreads();
    }
    #pragma unroll
    for (int nt = 0; nt < 4; ++nt) {
        int j = nbase + nt * 16 + c;
        float bj = bias[j];
        #pragma unroll
        for (int r = 0; r < 4; ++r) {
            int m = mbase + w * 16 + q * 4 + r;
            wxb[(size_t)m * H_ + j] = acc[nt][r] + bj;
        }
    }
}

// --------------- K2: recurrent scan ----------------------------------------
#define POLL_LOAD(qv, ap) \
    asm volatile("global_load_dwordx4 %0, %1, off sc0 sc1" : "=v"(qv) : "v"(ap))

__global__ __launch_bounds__(256, 1) void rnn_scan(
        const float* __restrict__ U, const float* __restrict__ wxb,
        const float* __restrict__ alpha, const float* __restrict__ beta,
        float* __restrict__ out, uint16_t* __restrict__ Hbuf) {
    __shared__ __align__(16) uint16_t Als[2][16][520];  // dbuf A staging, +8 pad
    __shared__ __align__(16) uint16_t Hstg[16][128];    // tagged h_new (bf16)

    const int bid = blockIdx.x;
    const int g = bid >> 2, s = bid & 3;
    const int tid = threadIdx.x;
    const int lane = tid & 63;
    const int w = tid >> 6;
    const int q = lane >> 4, c = lane & 15;

    float sa, sb;
    { float a = alpha[0], b = beta[0];
      sa = 1.f / (1.f + __expf(-a)); sb = 1.f / (1.f + __expf(-b)); }

    // Loop-invariant U B-frags: wave w owns ntiles 2w, 2w+1 of our 128-col slice.
    v8s Uf[2][16];
    #pragma unroll
    for (int nt = 0; nt < 2; ++nt) {
        int jg = s * 128 + (2 * w + nt) * 16 + c;
        #pragma unroll
        for (int kt = 0; kt < 16; ++kt) {
            const float* gp = U + (size_t)(kt * 32 + q * 8) * H_ + jg;
            union { v8s v; uint16_t u[8]; } pk;
            #pragma unroll
            for (int jj = 0; jj < 8; ++jj) pk.u[jj] = f2bf(gp[(size_t)jj * H_]);
            Uf[nt][kt] = pk.v;
        }
    }
    float hold[2][4];
    #pragma unroll
    for (int nt = 0; nt < 2; ++nt)
        #pragma unroll
        for (int r = 0; r < 4; ++r) hold[nt][r] = 0.f;

    // wx prefetch: one step ahead (loads issued ~1 step before consumption).
    float wxv[2][4], wxn[2][4];
    #pragma unroll
    for (int nt = 0; nt < 2; ++nt) {
        int jg = s * 128 + (2 * w + nt) * 16 + c;
        #pragma unroll
        for (int r = 0; r < 4; ++r) {
            int bg = g * 16 + q * 4 + r;
            wxn[nt][r] = __builtin_nontemporal_load(
                &wxb[((size_t)bg * T_ + 0) * H_ + jg]);
        }
    }

    // Poll chunk mapping: block footprint = rows g*16..+15, 512 cols = 16KB
    // = 1024 x 16B chunks. Thread owns chunks k = tid + 256*u4 (u4=0..3):
    // each wave instruction reads 1KB lane-contiguous (full granule merge).
    // Chunk k -> Hbuf u16 offset rowbase + k*8; LDS row k>>6, col (k&63)*8.
    const size_t rowbase = (size_t)(g * 16) * H_;
    u32x4 pq0 = {0,0,0,0}, pq1 = {0,0,0,0}, pq2 = {0,0,0,0}, pq3 = {0,0,0,0};

    for (int t = 0; t < T_; ++t) {
        const int p = t & 1;
        // rotate wx prefetch buffer
        #pragma unroll
        for (int nt = 0; nt < 2; ++nt)
            #pragma unroll
            for (int r = 0; r < 4; ++r) wxv[nt][r] = wxn[nt][r];

        // ---- B: poll (tagged data; loads issued at tail of t-1), then copy
        //      validated chunks into Als[p] ----
        if (t == 0) {
            u32x4 z = {0, 0, 0, 0};
            #pragma unroll
            for (int u4 = 0; u4 < 4; ++u4) {
                int k = tid + 256 * u4;
                *(u32x4*)&Als[0][k >> 6][(k & 63) * 8] = z;
            }
        } else {
            const uint16_t* hb = Hbuf + (size_t)p * (B_ * H_) + rowbase;
            const uint16_t* a0 = hb + (size_t)(tid + 0)   * 8;
            const uint16_t* a1 = hb + (size_t)(tid + 256) * 8;
            const uint16_t* a2 = hb + (size_t)(tid + 512) * 8;
            const uint16_t* a3 = hb + (size_t)(tid + 768) * 8;
            const uint32_t tau = (uint32_t)((t >> 1) & 1);
            for (int guard = 0; guard < (1 << 20); ++guard) {
                asm volatile("s_waitcnt vmcnt(0)"
                             : "+v"(pq0), "+v"(pq1), "+v"(pq2), "+v"(pq3));
                __builtin_amdgcn_sched_barrier(0);
                uint32_t bad;
                if (tau) {
                    u32x4 av4 = pq0 & pq1 & pq2 & pq3;
                    bad = ~(av4.x & av4.y & av4.z & av4.w);
                } else {
                    u32x4 ov4 = pq0 | pq1 | pq2 | pq3;
                    bad = ov4.x | ov4.y | ov4.z | ov4.w;
                }
                if (!((bad | (bad >> 16)) & 1u)) break;
                POLL_LOAD(pq0, a0); POLL_LOAD(pq1, a1);
                POLL_LOAD(pq2, a2); POLL_LOAD(pq3, a3);
            }
            {
                int k0 = tid;
                *(u32x4*)&Als[p][k0 >> 6][(k0 & 63) * 8] = pq0;
                int k1 = tid + 256;
                *(u32x4*)&Als[p][k1 >> 6][(k1 & 63) * 8] = pq1;
                int k2 = tid + 512;
                *(u32x4*)&Als[p][k2 >> 6][(k2 & 63) * 8] = pq2;
                int k3 = tid + 768;
                *(u32x4*)&Als[p][k3 >> 6][(k3 & 63) * 8] = pq3;
            }
        }
        __syncthreads();  // C: Als[p] complete
        // ---- prefetch wx for t+1 (max distance from the next poll wait) ----
        if (t + 1 < T_) {
            #pragma unroll
            for (int nt = 0; nt < 2; ++nt) {
                int jg = s * 128 + (2 * w + nt) * 16 + c;
                #pragma unroll
                for (int r = 0; r < 4; ++r) {
                    int bg = g * 16 + q * 4 + r;
                    wxn[nt][r] = __builtin_nontemporal_load(
                        &wxb[((size_t)bg * T_ + (t + 1)) * H_ + jg]);
                }
            }
        }
        // ---- D: P = H @ U_slice ----
        v4f acc0 = (v4f){0.f, 0.f, 0.f, 0.f};
        v4f acc1 = (v4f){0.f, 0.f, 0.f, 0.f};
        #pragma unroll
        for (int kt = 0; kt < 16; ++kt) {
            v8s a = *(const v8s*)((const uint16_t*)&Als[p][c][0] + kt * 32 + q * 8);
            acc0 = __builtin_amdgcn_mfma_f32_16x16x32_bf16(a, Uf[0][kt], acc0, 0, 0, 0);
            acc1 = __builtin_amdgcn_mfma_f32_16x16x32_bf16(a, Uf[1][kt], acc1, 0, 0, 0);
        }
        // ---- E: epilogue (fp32 state in regs); tagged bf16 -> Hstg ----
        const uint16_t tauw = (uint16_t)(((t + 1) >> 1) & 1);
        #pragma unroll
        for (int nt = 0; nt < 2; ++nt) {
            v4f av = nt ? acc1 : acc0;
            int jl = (2 * w + nt) * 16 + c;
            #pragma unroll
            for (int r = 0; r < 4; ++r) {
                float pre = av[r] + wxv[nt][r];
                float ex = __expf(pre + pre);                           // e^{2x}
                float ct = 1.f - 2.f * __builtin_amdgcn_rcpf(ex + 1.f); // tanh
                float hn = sb * hold[nt][r] + sa * ct;
                hold[nt][r] = hn;
                Hstg[q * 4 + r][jl] = (uint16_t)((f2bf(hn) & 0xFFFEu) | tauw);
            }
        }
        // ---- out stores early (plain, retire in local L2; keeps the vmcnt
        //      FIFO ahead of the tail's publish+poll loads) ----
        #pragma unroll
        for (int nt = 0; nt < 2; ++nt) {
            int jg = s * 128 + (2 * w + nt) * 16 + c;
            #pragma unroll
            for (int r = 0; r < 4; ++r) {
                int bg = g * 16 + q * 4 + r;
                out[((size_t)bg * T_ + t) * H_ + jg] = hold[nt][r];
            }
        }
        __syncthreads();  // F: Hstg complete
        // ---- G: publish — one coalesced dwordx4 store per thread ----
        {
            int b = tid >> 4, jo = (tid & 15) * 8;
            u32x4 val = *(const u32x4*)&Hstg[b][jo];
            uint16_t* pp = Hbuf +
                ((size_t)(1 - p) * B_ + g * 16 + b) * H_ + s * 128 + jo;
            asm volatile("global_store_dwordx4 %0, %1, off sc0 sc1"
                         :: "v"(pp), "v"(val) : "memory");
        }
        // ---- early-issue next poll loads: LLC RT overlaps loop tail/head;
        //      stale data is caught by the next tag check ----
        if (t + 1 < T_) {
            const uint16_t* hb = Hbuf + (size_t)(1 - p) * (B_ * H_) + rowbase;
            const uint16_t* a0 = hb + (size_t)(tid + 0)   * 8;
            const uint16_t* a1 = hb + (size_t)(tid + 256) * 8;
            const uint16_t* a2 = hb + (size_t)(tid + 512) * 8;
            const uint16_t* a3 = hb + (size_t)(tid + 768) * 8;
            POLL_LOAD(pq0, a0); POLL_LOAD(pq1, a1);
            POLL_LOAD(pq2, a2); POLL_LOAD(pq3, a3);
        }
    }
}

extern "C" void kernel_launch(void* const* d_in, const int* in_sizes, int n_in,
                              void* d_out, int out_size, void* d_ws, size_t ws_size,
                              hipStream_t stream) {
    const float* x     = (const float*)d_in[0];
    const float* W     = (const float*)d_in[1];
    const float* U     = (const float*)d_in[2];
    const float* bias  = (const float*)d_in[3];
    const float* alpha = (const float*)d_in[4];
    const float* beta  = (const float*)d_in[5];
    float* out = (float*)d_out;

    char* ws = (char*)d_ws;
    float* wxb = (float*)ws;                                  // 64 MiB
    uint16_t* Hbuf = (uint16_t*)(ws + WXB_BYTES);             // 128 KiB tagged bf16

    // Warm-up tag safety: parity 0 halves get LSB=0 (invalid at t'=2 which
    // expects tau=1), parity 1 halves get LSB=1 (invalid at t'=1, tau=0).
    hipMemsetAsync(Hbuf, 0x00, HHALF_BYTES, stream);
    hipMemsetAsync((char*)Hbuf + HHALF_BYTES, 0xFF, HHALF_BYTES, stream);

    wx_gemm<<<dim3((M_ / 64) * (H_ / 64)), dim3(256), 0, stream>>>(x, W, bias, wxb);
    rnn_scan<<<dim3(16), dim3(256), 0, stream>>>(U, wxb, alpha, beta, out, Hbuf);
}